// Round 8
// baseline (335.257 us; speedup 1.0000x reference)
//
#include <hip/hip_runtime.h>
#include <stdint.h>

#define TPE 4096
#define DM 512
#define HID 1408
#define NE 8

#define N4X   4194304   // 32768*512/4 (float4 count of x)
#define N4W12 2883584   // 8*2816*512/4

typedef unsigned short u16;
typedef __attribute__((ext_vector_type(8))) __bf16 bf16x8;
typedef __attribute__((ext_vector_type(4))) float f32x4;

__device__ __forceinline__ u16 f2bf(float f) {
  union { float f; uint32_t u; } v; v.f = f;
  uint32_t u = v.u;
  u += 0x7fffu + ((u >> 16) & 1u);   // round-to-nearest-even
  return (u16)(u >> 16);
}

__device__ __forceinline__ uint2 pack4(float4 v) {
  union { u16 s[4]; uint2 u2; } o;
  o.s[0] = f2bf(v.x); o.s[1] = f2bf(v.y); o.s[2] = f2bf(v.z); o.s[3] = f2bf(v.w);
  return o.u2;
}

// ---------------- f32 -> bf16 convert for x and w12, 4 float4/thread -------
// ILP depth 4: all loads issued before converts/stores. N4X/1024 = 4096, so
// each 256-thread x4 block lies wholly inside x (blockIdx < 4096) or w12.
__global__ void cvt_xw12(const float* __restrict__ x, const float* __restrict__ w12,
                         u16* __restrict__ xb, u16* __restrict__ w12b) {
  const int off = blockIdx.x * 1024 + threadIdx.x;   // float4 index of elem 0
  const float4* s4; uint2* d4;
  if (blockIdx.x < 4096) { s4 = reinterpret_cast<const float4*>(x) + off;
                           d4 = reinterpret_cast<uint2*>(xb) + off; }
  else                   { s4 = reinterpret_cast<const float4*>(w12) + (off - N4X);
                           d4 = reinterpret_cast<uint2*>(w12b) + (off - N4X); }
  float4 v0 = s4[0], v1 = s4[256], v2 = s4[512], v3 = s4[768];
  d4[0]   = pack4(v0);
  d4[256] = pack4(v1);
  d4[512] = pack4(v2);
  d4[768] = pack4(v3);
}

// ------------- global->LDS async stage, ROWS x 64 bf16 tile ----------------
// Row = 128 B. XOR swizzle at 16B-chunk granularity: global chunk c of row r
// lands at LDS chunk c^(r&7) -> b128 reads are 2-way aliased (free, m136).
// NWAVES*ROWS/32 must cover ROWS: works for (4 waves, ROWS=128/256) and
// (4 waves, ROWS=64).
template <int ROWS>
__device__ __forceinline__ void stage_tile64(u16* lds, const u16* g, int lda,
                                             int wave, int lane) {
  const int srow = lane >> 3;                 // 0..7 within 8-row window
  const int gchunk = (lane & 7) ^ srow;       // schunk ^ (grow & 7)
#pragma unroll
  for (int r = 0; r < ROWS / 32; ++r) {
    const int row0 = (wave * (ROWS / 32) + r) * 8;
    const u16* gp = g + (size_t)(row0 + srow) * lda + gchunk * 8;
    u16* lp = lds + row0 * 64;                // 64 u16 (=128B) per row
    __builtin_amdgcn_global_load_lds((const __attribute__((address_space(1))) void*)gp,
                                     (__attribute__((address_space(3))) void*)lp,
                                     16, 0, 0);
  }
}

__device__ __forceinline__ bf16x8 read_frag(const u16* lds, int row, int kchunk) {
  return *reinterpret_cast<const bf16x8*>(&lds[row * 64 + (((kchunk ^ (row & 7)) << 3))]);
}

// ---------------- GEMM1 + fused SwiGLU, XCD-pinned per expert --------------
// (R0-proven structure: 116 us / MfmaUtil 36% / 0 bank conflicts)
// grid (8, 352+44): blockIdx.x = e -> with flat%8 XCD round-robin, expert e's
// blocks all land on XCD e, so w12_e (2.9 MB bf16) stays L2-resident.
// y = mt*11 + nt (nt fastest) -> each A-tile reused 11x while L2-hot.
// y in [352,396): tail blocks convert w3 f32->bf16 (hidden under GEMM).
__global__ __launch_bounds__(256, 2)
void gemm1_swiglu(const u16* __restrict__ xb, const u16* __restrict__ w12b,
                  u16* __restrict__ hb, const float* __restrict__ w3f,
                  u16* __restrict__ w3b) {
  __shared__ u16 sA[128 * 64];
  __shared__ u16 sBg[128 * 64];
  __shared__ u16 sBu[128 * 64];
  const int e = blockIdx.x;
  const int y = blockIdx.y;
  const int tid = threadIdx.x;

  if (y >= 352) {   // w3 conversion tail: 352 blocks x 4096 float4
    const int c = e + 8 * (y - 352);          // 0..351
    const float4* src = reinterpret_cast<const float4*>(w3f) + (size_t)c * 4096;
    uint2* dst = reinterpret_cast<uint2*>(w3b) + (size_t)c * 4096;
#pragma unroll
    for (int it = 0; it < 16; ++it) {
      float4 v = src[it * 256 + tid];
      dst[it * 256 + tid] = pack4(v);
    }
    return;
  }

  const int mt = y / 11, nt = y % 11;
  const int wave = tid >> 6, lane = tid & 63;
  const int wm = wave >> 1, wn = wave & 1;
  const int quad = lane >> 4, rr = lane & 15;

  const u16* A  = xb + (size_t)(e * TPE + mt * 128) * DM;
  const u16* Bg = w12b + (size_t)e * (2 * HID) * DM + (size_t)(nt * 128) * DM;
  const u16* Bu = Bg + (size_t)HID * DM;

  f32x4 zero = {0.f, 0.f, 0.f, 0.f};
  f32x4 accg[4][4], accu[4][4];
#pragma unroll
  for (int i = 0; i < 4; ++i)
#pragma unroll
    for (int j = 0; j < 4; ++j) { accg[i][j] = zero; accu[i][j] = zero; }

  for (int k0 = 0; k0 < DM; k0 += 64) {
    stage_tile64<128>(sA, A + k0, DM, wave, lane);
    stage_tile64<128>(sBg, Bg + k0, DM, wave, lane);
    stage_tile64<128>(sBu, Bu + k0, DM, wave, lane);
    __syncthreads();

#pragma unroll
    for (int kk = 0; kk < 2; ++kk) {
      const int kc = kk * 4 + quad;
      bf16x8 af[4], bg[4], bu[4];
#pragma unroll
      for (int mi = 0; mi < 4; ++mi)
        af[mi] = read_frag(sA, wm * 64 + mi * 16 + rr, kc);
#pragma unroll
      for (int ni = 0; ni < 4; ++ni) {
        bg[ni] = read_frag(sBg, wn * 64 + ni * 16 + rr, kc);
        bu[ni] = read_frag(sBu, wn * 64 + ni * 16 + rr, kc);
      }
#pragma unroll
      for (int mi = 0; mi < 4; ++mi)
#pragma unroll
        for (int ni = 0; ni < 4; ++ni) {
          accg[mi][ni] = __builtin_amdgcn_mfma_f32_16x16x32_bf16(af[mi], bg[ni], accg[mi][ni], 0, 0, 0);
          accu[mi][ni] = __builtin_amdgcn_mfma_f32_16x16x32_bf16(af[mi], bu[ni], accu[mi][ni], 0, 0, 0);
        }
    }
    __syncthreads();
  }

  const size_t rowbase = (size_t)(e * TPE + mt * 128 + wm * 64);
  const int colbase = nt * 128 + wn * 64;
#pragma unroll
  for (int mi = 0; mi < 4; ++mi)
#pragma unroll
    for (int ni = 0; ni < 4; ++ni)
#pragma unroll
      for (int r2 = 0; r2 < 4; ++r2) {
        float g = accg[mi][ni][r2];
        float u = accu[mi][ni][r2];
        float s = (g / (1.f + __expf(-g))) * u;
        size_t row = rowbase + mi * 16 + quad * 4 + r2;
        int col = colbase + ni * 16 + rr;
        hb[row * HID + col] = f2bf(s);
      }
}

// ---------------- GEMM2: h @ w3^T -> out (f32), 64x256, 4 blocks/CU --------
// Traffic-invariant occupancy test: BN=256 keeps hb reads at 2x (184 MB,
// same as R0's 128x256); BM=64 shrinks LDS to 40 KB -> 4 blocks/CU and a
// 4-round block queue (vs R0's single resident round) for m114 drain overlap.
// grid (8, 128): x = e -> XCD pin (w3_e 1.4 MB L2-resident);
// y = mt*2 + nt (nt fastest -> hb A-tile reused 2x while L2-hot).
__global__ __launch_bounds__(256, 4)
void gemm2(const u16* __restrict__ hb, const u16* __restrict__ w3b,
           float* __restrict__ out) {
  __shared__ u16 sA[64 * 64];      // 8 KB
  __shared__ u16 sB[256 * 64];     // 32 KB
  const int e = blockIdx.x;
  const int mt = blockIdx.y >> 1, nt = blockIdx.y & 1;
  const int tid = threadIdx.x, wave = tid >> 6, lane = tid & 63;
  const int wm = wave >> 1, wn = wave & 1;    // 2 (M) x 2 (N) waves
  const int quad = lane >> 4, rr = lane & 15;

  const u16* A = hb + (size_t)(e * TPE + mt * 64) * HID;
  const u16* B = w3b + (size_t)e * DM * HID + (size_t)(nt * 256) * HID;

  f32x4 zero = {0.f, 0.f, 0.f, 0.f};
  f32x4 acc[2][8];
#pragma unroll
  for (int i = 0; i < 2; ++i)
#pragma unroll
    for (int j = 0; j < 8; ++j) acc[i][j] = zero;

  for (int k0 = 0; k0 < HID; k0 += 64) {
    stage_tile64<64>(sA, A + k0, HID, wave, lane);
    stage_tile64<256>(sB, B + k0, HID, wave, lane);
    __syncthreads();

#pragma unroll
    for (int kk = 0; kk < 2; ++kk) {
      const int kc = kk * 4 + quad;
      bf16x8 af[2], bfr[8];
#pragma unroll
      for (int mi = 0; mi < 2; ++mi)
        af[mi] = read_frag(sA, wm * 32 + mi * 16 + rr, kc);
#pragma unroll
      for (int ni = 0; ni < 8; ++ni)
        bfr[ni] = read_frag(sB, wn * 128 + ni * 16 + rr, kc);
#pragma unroll
      for (int mi = 0; mi < 2; ++mi)
#pragma unroll
        for (int ni = 0; ni < 8; ++ni)
          acc[mi][ni] = __builtin_amdgcn_mfma_f32_16x16x32_bf16(af[mi], bfr[ni], acc[mi][ni], 0, 0, 0);
    }
    __syncthreads();
  }

  const size_t rowbase = (size_t)(e * TPE + mt * 64 + wm * 32);
  const int colbase = nt * 256 + wn * 128;
#pragma unroll
  for (int mi = 0; mi < 2; ++mi)
#pragma unroll
    for (int ni = 0; ni < 8; ++ni)
#pragma unroll
      for (int r2 = 0; r2 < 4; ++r2) {
        size_t row = rowbase + mi * 16 + quad * 4 + r2;
        int col = colbase + ni * 16 + rr;
        out[row * DM + col] = acc[mi][ni][r2];
      }
}

// ---------------------------------------------------------------------------
extern "C" void kernel_launch(void* const* d_in, const int* in_sizes, int n_in,
                              void* d_out, int out_size, void* d_ws, size_t ws_size,
                              hipStream_t stream) {
  (void)in_sizes; (void)n_in; (void)out_size; (void)ws_size;
  const float* x   = (const float*)d_in[0];
  const float* w12 = (const float*)d_in[1];
  const float* w3  = (const float*)d_in[2];
  float* out = (float*)d_out;

  char* ws = (char*)d_ws;
  u16* xb   = (u16*)(ws);
  u16* w12b = (u16*)(ws + (size_t)33554432);
  u16* w3b  = (u16*)(ws + (size_t)33554432 + 23068672);
  u16* hb   = (u16*)(ws + (size_t)33554432 + 23068672 + 11534336);

  // cvt: (N4X+N4W12)/1024 = 6912 blocks, 4 float4 per thread (ILP)
  cvt_xw12<<<6912, 256, 0, stream>>>(x, w12, xb, w12b);

  // gemm1: XCD-pinned (x=e); y = mt*11+nt for tiles, y>=352 converts w3
  gemm1_swiglu<<<dim3(8, 352 + 44), 256, 0, stream>>>(xb, w12b, hb, w3, w3b);
  // gemm2: XCD-pinned; 1024 blocks -> 4/CU, traffic same as 128x256
  gemm2<<<dim3(8, 128), 256, 0, stream>>>(hb, w3b, out);
}